// Round 14
// baseline (717.819 us; speedup 1.0000x reference)
//
#include <hip/hip_runtime.h>
#include <hip/hip_fp16.h>
#include <math.h>

#define NN 50000
#define EE 800000
#define NPAD 50048            // 782 * 64, row-tile padded
#define HEADS 4
#define HIDD 64
#define OUTF 32

struct __align__(8)  h4v { __half2 a, b; };
struct __align__(16) h8v { __half2 a, b, c, d; };   // 4 K-halves + 4 V-halves

typedef __attribute__((ext_vector_type(8))) _Float16 f16x8;
typedef __attribute__((ext_vector_type(4))) _Float16 f16x4;
typedef __attribute__((ext_vector_type(4))) float    f32x4;

// ---------------- prep: X fp32 -> f16, zero-padded to NPAD rows ----------------
__global__ __launch_bounds__(256) void prep_x(const float* __restrict__ X,
                                              _Float16* __restrict__ Xh)
{
    int li = blockIdx.x * 256 + threadIdx.x;       // over NPAD*128/4 float4s
    if (li >= NPAD * 32) return;
    int r = li >> 5, c4 = li & 31;
    float4 a4 = {0.f, 0.f, 0.f, 0.f};
    if (r < NN) a4 = *(const float4*)&X[(size_t)r * 128 + c4 * 4];
    f16x4 hv = { (_Float16)a4.x, (_Float16)a4.y, (_Float16)a4.z, (_Float16)a4.w };
    *(f16x4*)&Xh[(size_t)r * 128 + c4 * 4] = hv;
}

// ---------------- prep: W [k][col] fp32 -> WT [col][k] f16 ----------------
__global__ __launch_bounds__(256) void transpose_w(const float* __restrict__ src,
                                                   _Float16* __restrict__ dst,
                                                   int K, int COLS)
{
    int idx = blockIdx.x * 256 + threadIdx.x;
    if (idx >= K * COLS) return;
    int k = idx / COLS, col = idx % COLS;
    dst[(size_t)col * K + k] = (_Float16)src[idx];
}

// ---------------- prep: zero pad rows NN..NPAD of f16 H buffer ----------------
__global__ __launch_bounds__(256) void pad_h(_Float16* __restrict__ Hh)
{
    int idx = blockIdx.x * 256 + threadIdx.x;      // (NPAD-NN)*64 = 3072
    if (idx >= (NPAD - NN) * 64) return;
    Hh[(size_t)NN * 64 + idx] = (_Float16)0.f;
}

// ---------------- fused QKV+skip GEMM via f16 MFMA, LDS-free ----------------
// Grid: 13 * (NPAD/64) blocks, bijective XCD remap (13 tiles of one X strip on
// one XCD -> strip L2-resident; W broadcast L2-hot). Block 256 = 4 waves, each
// wave 16 rows x 64 cols. A-fragment: ONE f16x8 (16B) global load per k-step;
// B-fragments: 4 f16x8 loads from pre-transposed WT. No LDS, no barriers.
// A/B share k-indexing (k0+lg*8+j) -> HW k-permutation cancels (verified r9).
// tiles 0..3 -> Q (fp32), 4..7 -> K, 8..11 -> V (f16 interleaved KV), 12 -> SKIP
template<int KDIM>
__global__ __launch_bounds__(256) void qkvs_gemm(
    const _Float16* __restrict__ A,       // [NPAD][KDIM] f16, padded
    const _Float16* __restrict__ WT,      // [q|k|v|s] each [col][KDIM] f16
    const float* __restrict__ bq, const float* __restrict__ bk,
    const float* __restrict__ bv, const float* __restrict__ bs,
    float* __restrict__ Q, __half* __restrict__ KV, float* __restrict__ SKP)
{
    // bijective XCD remap
    const int nwg = gridDim.x;
    const int i   = blockIdx.x;
    const int q8  = nwg >> 3, r8 = nwg & 7;
    const int xcd = i & 7, j = i >> 3;
    const int w   = (xcd < r8 ? xcd * (q8 + 1) : r8 * (q8 + 1) + (xcd - r8) * q8) + j;

    const int nt   = w % 13;
    const int row0 = (w / 13) * 64;

    const float* bias; int mode, bcol;
    if (nt < 4)       { bias = bq; mode = 0; bcol = nt * 64; }
    else if (nt < 8)  { bias = bk; mode = 1; bcol = (nt - 4) * 64; }
    else if (nt < 12) { bias = bv; mode = 2; bcol = (nt - 8) * 64; }
    else              { bias = bs; mode = 3; bcol = 0; }
    // WT tile base: matrices packed q(256 cols) | k(256) | v(256) | s(64)
    const _Float16* WTt = WT + ((size_t)mode * 256 + bcol) * KDIM;

    const int tid = threadIdx.x;
    const int lane = tid & 63, wvi = tid >> 6;
    const int lr = lane & 15, lg = lane >> 4;
    const size_t arow = row0 + wvi * 16 + lr;

    f32x4 acc[4];
    #pragma unroll
    for (int ci = 0; ci < 4; ++ci) acc[ci] = (f32x4){0.f, 0.f, 0.f, 0.f};

    #pragma unroll
    for (int k0 = 0; k0 < KDIM; k0 += 32) {
        f16x8 af = *(const f16x8*)&A[arow * KDIM + k0 + lg * 8];
        #pragma unroll
        for (int ci = 0; ci < 4; ++ci) {
            f16x8 bf = *(const f16x8*)&WTt[(size_t)(ci * 16 + lr) * KDIM + k0 + lg * 8];
            acc[ci] = __builtin_amdgcn_mfma_f32_16x16x32_f16(af, bf, acc[ci], 0, 0, 0);
        }
    }

    // epilogue: bias + store (D: row=(lane>>4)*4+ii, col=lane&15)
    #pragma unroll
    for (int ci = 0; ci < 4; ++ci) {
        const int col = ci * 16 + lr;
        const float bia = bias[bcol + col];
        #pragma unroll
        for (int ii = 0; ii < 4; ++ii) {
            int gr = row0 + wvi * 16 + lg * 4 + ii;
            if (gr >= NN) continue;
            float o = acc[ci][ii] + bia;
            if (mode == 0) {
                Q[(size_t)gr * 256 + bcol + col] = o;
            } else if (mode == 3) {
                SKP[(size_t)gr * 64 + col] = o;
            } else {
                int h = bcol >> 6;
                int d = col;
                size_t idx = (size_t)gr * 512 + h * 128 + ((d >> 2) << 3) + (d & 3)
                             + (mode == 2 ? 4 : 0);
                KV[idx] = __float2half(o);
            }
        }
    }
}

// ---------------- CSR build (dst-bucketed), reused by both layers ----------------
__global__ __launch_bounds__(256) void hist_kernel(const int* __restrict__ dstA,
                                                   int* __restrict__ deg)
{
    int e = blockIdx.x * 256 + threadIdx.x;   // EE divisible by 256
    atomicAdd(&deg[dstA[e]], 1);
}

__global__ __launch_bounds__(1024) void scan_kernel(const int* __restrict__ deg,
                                                    int* __restrict__ rowptr,
                                                    int* __restrict__ cursor)
{
    __shared__ int sdata[1024];
    __shared__ int soff;
    const int tid = threadIdx.x;
    if (tid == 0) soff = 0;
    __syncthreads();
    for (int base = 0; base < NN; base += 1024) {
        int v = (base + tid < NN) ? deg[base + tid] : 0;
        sdata[tid] = v;
        __syncthreads();
        #pragma unroll
        for (int off = 1; off < 1024; off <<= 1) {
            int t = (tid >= off) ? sdata[tid - off] : 0;
            __syncthreads();
            sdata[tid] += t;
            __syncthreads();
        }
        int excl = sdata[tid] - v;
        if (base + tid < NN) {
            rowptr[base + tid] = soff + excl;
            cursor[base + tid] = soff + excl;
        }
        int total = sdata[1023];
        __syncthreads();
        if (tid == 0) soff += total;
        __syncthreads();
    }
    if (tid == 0) rowptr[NN] = EE;
}

__global__ __launch_bounds__(256) void scatter_kernel(const int* __restrict__ srcA,
                                                      const int* __restrict__ dstA,
                                                      int* __restrict__ cursor,
                                                      int* __restrict__ colidx)
{
    int e = blockIdx.x * 256 + threadIdx.x;
    int p = atomicAdd(&cursor[dstA[e]], 1);
    colidx[p] = srcA[e];
}

// ---------------- fused node-centric attention + head-mean + skip + LN ----------------
// one wave per node; lane: h = lane>>4 (head), t = lane&15.
// ONE 16B load per edge per lane (K-chunk + V-chunk interleaved). Output f16.
template<bool RELU>
__global__ __launch_bounds__(256) void node_attn(
    const int* __restrict__ rowptr, const int* __restrict__ colidx,
    const float* __restrict__ Q, const __half* __restrict__ KV,
    const float* __restrict__ SKP,
    const float* __restrict__ g, const float* __restrict__ b,
    __half* __restrict__ Hout)
{
    int n = (blockIdx.x * blockDim.x + threadIdx.x) >> 6;
    if (n >= NN) return;
    const int lane = threadIdx.x & 63;
    const int h = lane >> 4, t = lane & 15;
    const int kvoff = h * 128 + t * 8;

    const float4 q4 = *(const float4*)&Q[(size_t)n * 256 + h * 64 + t * 4];

    float4 acc = {0.f, 0.f, 0.f, 0.f};
    float ssum = 0.f;
    const int e0 = rowptr[n], e1 = rowptr[n + 1];
    int e = e0;
    for (; e + 2 <= e1; e += 2) {
        const int s0 = colidx[e], s1 = colidx[e + 1];
        const h8v kv0 = *(const h8v*)&KV[(size_t)s0 * 512 + kvoff];
        const h8v kv1 = *(const h8v*)&KV[(size_t)s1 * 512 + kvoff];
        const float2 k0a = __half22float2(kv0.a), k0b = __half22float2(kv0.b);
        const float2 k1a = __half22float2(kv1.a), k1b = __half22float2(kv1.b);
        float p0 = q4.x * k0a.x + q4.y * k0a.y + q4.z * k0b.x + q4.w * k0b.y;
        float p1 = q4.x * k1a.x + q4.y * k1a.y + q4.z * k1b.x + q4.w * k1b.y;
        p0 += __shfl_xor(p0, 1);  p1 += __shfl_xor(p1, 1);
        p0 += __shfl_xor(p0, 2);  p1 += __shfl_xor(p1, 2);
        p0 += __shfl_xor(p0, 4);  p1 += __shfl_xor(p1, 4);
        p0 += __shfl_xor(p0, 8);  p1 += __shfl_xor(p1, 8);
        const float eh0 = __expf(p0 * 0.125f);
        const float eh1 = __expf(p1 * 0.125f);
        const float2 v0a = __half22float2(kv0.c), v0b = __half22float2(kv0.d);
        const float2 v1a = __half22float2(kv1.c), v1b = __half22float2(kv1.d);
        ssum  += eh0 + eh1;
        acc.x += eh0 * v0a.x + eh1 * v1a.x;
        acc.y += eh0 * v0a.y + eh1 * v1a.y;
        acc.z += eh0 * v0b.x + eh1 * v1b.x;
        acc.w += eh0 * v0b.y + eh1 * v1b.y;
    }
    for (; e < e1; ++e) {
        const int s = colidx[e];
        const h8v kv = *(const h8v*)&KV[(size_t)s * 512 + kvoff];
        const float2 ka = __half22float2(kv.a), kb = __half22float2(kv.b);
        float p = q4.x * ka.x + q4.y * ka.y + q4.z * kb.x + q4.w * kb.y;
        p += __shfl_xor(p, 1);
        p += __shfl_xor(p, 2);
        p += __shfl_xor(p, 4);
        p += __shfl_xor(p, 8);
        const float eh = __expf(p * 0.125f);
        const float2 va = __half22float2(kv.c), vb = __half22float2(kv.d);
        ssum  += eh;
        acc.x += eh * va.x; acc.y += eh * va.y; acc.z += eh * vb.x; acc.w += eh * vb.y;
    }
    const float inv = (ssum != 0.f) ? 1.f / ssum : 0.f;   // empty-segment guard
    acc.x *= inv; acc.y *= inv; acc.z *= inv; acc.w *= inv;

    // mean over heads
    #pragma unroll
    for (int o = 16; o < 64; o <<= 1) {
        acc.x += __shfl_xor(acc.x, o); acc.y += __shfl_xor(acc.y, o);
        acc.z += __shfl_xor(acc.z, o); acc.w += __shfl_xor(acc.w, o);
    }
    const float4 sk4 = *(const float4*)&SKP[(size_t)n * 64 + t * 4];
    float4 val;
    val.x = acc.x * 0.25f + sk4.x; val.y = acc.y * 0.25f + sk4.y;
    val.z = acc.z * 0.25f + sk4.z; val.w = acc.w * 0.25f + sk4.w;

    // LayerNorm over 64 dims
    float m  = val.x + val.y + val.z + val.w;
    float m2 = val.x * val.x + val.y * val.y + val.z * val.z + val.w * val.w;
    #pragma unroll
    for (int o = 1; o < 16; o <<= 1) { m += __shfl_xor(m, o); m2 += __shfl_xor(m2, o); }
    m *= (1.f / 64.f); m2 *= (1.f / 64.f);
    const float rstd = rsqrtf(m2 - m * m + 1e-5f);
    const float4 g4 = *(const float4*)&g[t * 4];
    const float4 b4 = *(const float4*)&b[t * 4];
    float4 y;
    y.x = (val.x - m) * rstd * g4.x + b4.x;
    y.y = (val.y - m) * rstd * g4.y + b4.y;
    y.z = (val.z - m) * rstd * g4.z + b4.z;
    y.w = (val.w - m) * rstd * g4.w + b4.w;
    if (RELU) {
        y.x = fmaxf(y.x, 0.f); y.y = fmaxf(y.y, 0.f);
        y.z = fmaxf(y.z, 0.f); y.w = fmaxf(y.w, 0.f);
    }
    if (h == 0) {
        h4v hv;
        hv.a = __floats2half2_rn(y.x, y.y);
        hv.b = __floats2half2_rn(y.z, y.w);
        *(h4v*)&Hout[(size_t)n * 64 + t * 4] = hv;
    }
}

// ---------------- final 64->32 linear (f16 input) ----------------
__global__ __launch_bounds__(256) void final_gemm(
    const __half* __restrict__ H, const float* __restrict__ Wf,
    const float* __restrict__ bf, float* __restrict__ out)
{
    __shared__ float sW[64][32];
    __shared__ float sH[8][64];
    const int tid = threadIdx.x;
    #pragma unroll
    for (int i = 0; i < 8; ++i) {
        int li = tid + 256 * i;
        sW[li >> 5][li & 31] = Wf[li];
    }
    const int n0 = blockIdx.x * 8;
    #pragma unroll
    for (int i = 0; i < 2; ++i) {
        int li = tid + 256 * i;
        int r = li >> 6, d = li & 63;
        int gn = n0 + r;
        sH[r][d] = (gn < NN) ? __half2float(H[(size_t)gn * 64 + d]) : 0.f;
    }
    __syncthreads();
    const int o = tid & 31, nl = tid >> 5;
    const int gn = n0 + nl;
    if (gn >= NN) return;
    float acc = bf[o];
    #pragma unroll
    for (int dd = 0; dd < 64; ++dd) acc += sH[nl][dd] * sW[dd][o];
    out[(size_t)gn * 32 + o] = acc;
}

extern "C" void kernel_launch(void* const* d_in, const int* in_sizes, int n_in,
                              void* d_out, int out_size, void* d_ws, size_t ws_size,
                              hipStream_t stream) {
    const float* x   = (const float*)d_in[0];
    const int*   ei  = (const int*)d_in[1];
    const int* srcA = ei;
    const int* dstA = ei + EE;
    const float *Wq1=(const float*)d_in[2],  *bq1=(const float*)d_in[3];
    const float *Wk1=(const float*)d_in[4],  *bk1=(const float*)d_in[5];
    const float *Wv1=(const float*)d_in[6],  *bv1=(const float*)d_in[7];
    const float *Ws1=(const float*)d_in[8],  *bs1=(const float*)d_in[9];
    const float *Wq2=(const float*)d_in[10], *bq2=(const float*)d_in[11];
    const float *Wk2=(const float*)d_in[12], *bk2=(const float*)d_in[13];
    const float *Wv2=(const float*)d_in[14], *bv2=(const float*)d_in[15];
    const float *Ws2=(const float*)d_in[16], *bs2=(const float*)d_in[17];
    const float *ln_g=(const float*)d_in[18],*ln_b=(const float*)d_in[19];
    const float *Wf=(const float*)d_in[20],  *bf=(const float*)d_in[21];
    float* out = (float*)d_out;

    float* ws = (float*)d_ws;
    size_t off = 0;
    float* Q      = ws + off; off += (size_t)NN * 256;
    __half* KV    = (__half*)(ws + off); off += (size_t)NN * 256;   // NN*512 halves
    float* SKP    = ws + off; off += (size_t)NN * 64;
    _Float16* Xh  = (_Float16*)(ws + off); off += (size_t)NPAD * 64;  // NPAD*128 halves
    __half* H1h   = (__half*)(ws + off); off += (size_t)NPAD * 32;    // NPAD*64 halves
    __half* H2h   = (__half*)(ws + off); off += (size_t)NPAD * 32;
    _Float16* WT1 = (_Float16*)(ws + off); off += (832 * 128) / 2;    // 832 cols x 128
    _Float16* WT2 = (_Float16*)(ws + off); off += (832 * 64) / 2;     // 832 cols x 64
    int* deg    = (int*)(ws + off); off += NN;
    int* rowptr = (int*)(ws + off); off += NN + 1;
    int* cursor = (int*)(ws + off); off += NN;
    int* colidx = (int*)(ws + off); off += EE;

    const int rowTiles   = NPAD / 64;            // 782
    const int gemmGrid   = 13 * rowTiles;        // 10166
    const int edgeBlocks = EE / 256;             // 3125
    const int nodeBlocks = NN / 4;               // 12500

    // ---- prep: f16 conversions + weight transposes (independent of graph) ----
    prep_x<<<(NPAD * 32 + 255) / 256, 256, 0, stream>>>(x, Xh);
    transpose_w<<<(128 * 256 + 255) / 256, 256, 0, stream>>>(Wq1, WT1 + 0,            128, 256);
    transpose_w<<<(128 * 256 + 255) / 256, 256, 0, stream>>>(Wk1, WT1 + 256 * 128,    128, 256);
    transpose_w<<<(128 * 256 + 255) / 256, 256, 0, stream>>>(Wv1, WT1 + 512 * 128,    128, 256);
    transpose_w<<<(128 * 64  + 255) / 256, 256, 0, stream>>>(Ws1, WT1 + 768 * 128,    128, 64);
    transpose_w<<<(64 * 256  + 255) / 256, 256, 0, stream>>>(Wq2, WT2 + 0,            64, 256);
    transpose_w<<<(64 * 256  + 255) / 256, 256, 0, stream>>>(Wk2, WT2 + 256 * 64,     64, 256);
    transpose_w<<<(64 * 256  + 255) / 256, 256, 0, stream>>>(Wv2, WT2 + 512 * 64,     64, 256);
    transpose_w<<<(64 * 64   + 255) / 256, 256, 0, stream>>>(Ws2, WT2 + 768 * 64,     64, 64);
    pad_h<<<((NPAD - NN) * 64 + 255) / 256, 256, 0, stream>>>((_Float16*)H1h);

    // ---- CSR build (dst-bucketed), used by both layers ----
    hipMemsetAsync(deg, 0, NN * sizeof(int), stream);
    hist_kernel<<<edgeBlocks, 256, 0, stream>>>(dstA, deg);
    scan_kernel<<<1, 1024, 0, stream>>>(deg, rowptr, cursor);
    scatter_kernel<<<edgeBlocks, 256, 0, stream>>>(srcA, dstA, cursor, colidx);

    // ---- layer 1 ----
    qkvs_gemm<128><<<gemmGrid, 256, 0, stream>>>(Xh, WT1, bq1, bk1, bv1, bs1,
                                                 Q, KV, SKP);
    node_attn<true><<<nodeBlocks, 256, 0, stream>>>(rowptr, colidx, Q, KV, SKP,
                                                    ln_g, ln_b, H1h);

    // ---- layer 2 ----
    qkvs_gemm<64><<<gemmGrid, 256, 0, stream>>>((const _Float16*)H1h, WT2,
                                                bq2, bk2, bv2, bs2, Q, KV, SKP);
    node_attn<false><<<nodeBlocks, 256, 0, stream>>>(rowptr, colidx, Q, KV, SKP,
                                                     ln_g, ln_b, H2h);

    // ---- final linear ----
    final_gemm<<<NN / 8, 256, 0, stream>>>(H2h, Wf, bf, out);
}